// Round 1
// baseline (597.815 us; speedup 1.0000x reference)
//
#include <hip/hip_runtime.h>

#define N_B  64
#define DIN  1024
#define DOUT 256
#define EPS  1e-4f   // LR * LR

// ---- output offsets (floats) ----
#define OUT_MNEW  0
#define OUT_STATE (N_B * DIN * DOUT)          // 16777216
#define OUT_LL    (OUT_STATE + 1)
#define OUT_RR    (OUT_LL + N_B * DIN)

// ---- workspace offsets (floats) ----
#define WS_COLPART 0                            // [N][64][256] per-wave col partials
#define WS_A_SCALE (N_B * 64 * 256)             // [N][1024]  ll^-1/4
#define WS_B_SCALE (WS_A_SCALE + N_B * DIN)     // [N][256]   rr^-1/4
#define WS_T       (WS_B_SCALE + N_B * DOUT)    // [N][256][256]  T, later Eh
#define WS_ABUF    (WS_T + N_B * DOUT * DOUT)   // [N][1024][256] A = M - eps*PP

// ============================================================
// K1: row sums of grad^2 -> ll (output) and a=ll^-0.25 ; per-wave col partials
// grid 1024 = 64 n * 16 chunks, block 256 (4 waves, 16 rows each)
// ============================================================
__global__ __launch_bounds__(256) void k_moments(
    const float* __restrict__ grad, const float* __restrict__ L0,
    float* __restrict__ out, float* __restrict__ ws)
{
    const int n     = blockIdx.x >> 4;
    const int chunk = blockIdx.x & 15;
    const int wave  = threadIdx.x >> 6;
    const int lane  = threadIdx.x & 63;
    const float* gbase = grad + (size_t)n * DIN * DOUT;

    float4 cacc = make_float4(0.f, 0.f, 0.f, 0.f);
    const int i0 = chunk * 64 + wave * 16;
    #pragma unroll 4
    for (int r = 0; r < 16; ++r) {
        const int i = i0 + r;
        const float4 v = *(const float4*)(gbase + (size_t)i * DOUT + lane * 4);
        float s = v.x*v.x + v.y*v.y + v.z*v.z + v.w*v.w;
        cacc.x += v.x*v.x; cacc.y += v.y*v.y; cacc.z += v.z*v.z; cacc.w += v.w*v.w;
        #pragma unroll
        for (int off = 32; off; off >>= 1) s += __shfl_xor(s, off);
        if (lane == 0) {
            const float l0 = L0[n * DIN + i];
            const float ll = fmaxf(l0, 0.5f * l0 + s * (0.5f / DOUT));
            out[OUT_LL + n * DIN + i] = ll;
            ws[WS_A_SCALE + n * DIN + i] = rsqrtf(sqrtf(ll));
        }
    }
    const int slot = chunk * 4 + wave;   // 0..63
    *(float4*)(ws + WS_COLPART + ((size_t)(n * 64 + slot)) * 256 + lane * 4) = cacc;
}

// ============================================================
// K2: reduce col partials -> rr (output), b = rr^-0.25 ; copy state
// grid 64, block 256
// ============================================================
__global__ __launch_bounds__(256) void k_cols(
    const float* __restrict__ R0, const float* __restrict__ state,
    float* __restrict__ out, float* __restrict__ ws)
{
    const int n = blockIdx.x, o = threadIdx.x;
    const float* cp = ws + WS_COLPART + (size_t)n * 64 * 256 + o;
    float s = 0.f;
    #pragma unroll 8
    for (int k = 0; k < 64; ++k) s += cp[k * 256];
    const float r0 = R0[n * DOUT + o];
    const float rr = fmaxf(r0, 0.5f * r0 + s * (0.5f / DIN));
    out[OUT_RR + n * DOUT + o] = rr;
    ws[WS_B_SCALE + n * DOUT + o] = rsqrtf(sqrtf(rr));
    if (blockIdx.x == 0 && threadIdx.x == 0) out[OUT_STATE] = state[0];
}

// ============================================================
// K3: T[n][p][o] = b[o] * sum_i M[n][i][p] * (a[i]*grad[n][i][o])
// "A^T B" GEMM, K=1024, out 256x256. grid 1024 = 64 n * 16 tiles, block 256.
// ============================================================
__global__ __launch_bounds__(256) void k_T(
    const float* __restrict__ M, const float* __restrict__ grad,
    float* __restrict__ ws)
{
    __shared__ float sA[64][68];
    __shared__ float sB[64][68];
    const int n  = blockIdx.x >> 4;
    const int p0 = ((blockIdx.x >> 2) & 3) * 64;
    const int o0 = (blockIdx.x & 3) * 64;
    const int tid = threadIdx.x;
    const int to = tid & 15, tp = tid >> 4;
    const float* Mb = M    + (size_t)n * DIN * DOUT;
    const float* Gb = grad + (size_t)n * DIN * DOUT;
    const float* av = ws + WS_A_SCALE + n * DIN;

    float acc[4][4] = {};
    for (int kb = 0; kb < DIN; kb += 64) {
        #pragma unroll
        for (int t = 0; t < 16; ++t) {
            const int e = tid + t * 256;
            const int kk = e >> 6, cc = e & 63;
            sA[kk][cc] = Mb[(size_t)(kb + kk) * DOUT + p0 + cc];
            sB[kk][cc] = Gb[(size_t)(kb + kk) * DOUT + o0 + cc] * av[kb + kk];
        }
        __syncthreads();
        #pragma unroll 8
        for (int kk = 0; kk < 64; ++kk) {
            const float4 a4 = *(const float4*)(&sA[kk][tp * 4]);
            const float4 b4 = *(const float4*)(&sB[kk][to * 4]);
            const float xs[4] = {a4.x, a4.y, a4.z, a4.w};
            const float ys[4] = {b4.x, b4.y, b4.z, b4.w};
            #pragma unroll
            for (int r = 0; r < 4; ++r)
                #pragma unroll
                for (int c = 0; c < 4; ++c)
                    acc[r][c] = fmaf(xs[r], ys[c], acc[r][c]);
        }
        __syncthreads();
    }
    const float* bv = ws + WS_B_SCALE + n * DOUT;
    float* T = ws + WS_T + (size_t)n * DOUT * DOUT;
    const float4 b4 = *(const float4*)(&bv[o0 + to * 4]);
    const float bs[4] = {b4.x, b4.y, b4.z, b4.w};
    #pragma unroll
    for (int r = 0; r < 4; ++r) {
        const int p = p0 + tp * 4 + r;
        float4 res;
        res.x = acc[r][0] * bs[0]; res.y = acc[r][1] * bs[1];
        res.z = acc[r][2] * bs[2]; res.w = acc[r][3] * bs[3];
        *(float4*)(&T[(size_t)p * DOUT + o0 + to * 4]) = res;
    }
}

// ============================================================
// K4: A[n][i][o] = M + EPS*( (M*T)[i][o] - a[i]*b[o]*grad )
// GEMM [1024x256] x [256x256], K=256. grid 4096 = 64 n * (16 i-tiles * 4 o-tiles).
// ============================================================
__global__ __launch_bounds__(256) void k_Abuild(
    const float* __restrict__ M, const float* __restrict__ grad,
    float* __restrict__ ws)
{
    __shared__ float sXt[64][68];  // [k][i] transposed
    __shared__ float sY[64][68];   // [k][o]
    const int n  = blockIdx.x >> 6;
    const int i0 = ((blockIdx.x >> 2) & 15) * 64;
    const int o0 = (blockIdx.x & 3) * 64;
    const int tid = threadIdx.x;
    const int to = tid & 15, ti = tid >> 4;
    const float* Mb = M + (size_t)n * DIN * DOUT;
    const float* T  = ws + WS_T + (size_t)n * DOUT * DOUT;

    float acc[4][4] = {};
    for (int kb = 0; kb < DOUT; kb += 64) {
        #pragma unroll
        for (int t = 0; t < 16; ++t) {
            const int e = tid + t * 256;
            const int rr = e >> 6, cc = e & 63;
            sXt[cc][rr] = Mb[(size_t)(i0 + rr) * DOUT + kb + cc];
            sY[rr][cc]  = T[(size_t)(kb + rr) * DOUT + o0 + cc];
        }
        __syncthreads();
        #pragma unroll 8
        for (int kk = 0; kk < 64; ++kk) {
            const float4 x4 = *(const float4*)(&sXt[kk][ti * 4]);
            const float4 y4 = *(const float4*)(&sY[kk][to * 4]);
            const float xs[4] = {x4.x, x4.y, x4.z, x4.w};
            const float ys[4] = {y4.x, y4.y, y4.z, y4.w};
            #pragma unroll
            for (int r = 0; r < 4; ++r)
                #pragma unroll
                for (int c = 0; c < 4; ++c)
                    acc[r][c] = fmaf(xs[r], ys[c], acc[r][c]);
        }
        __syncthreads();
    }
    const float* av = ws + WS_A_SCALE + n * DIN;
    const float* bv = ws + WS_B_SCALE + n * DOUT;
    const float* Gb = grad + (size_t)n * DIN * DOUT;
    float* Ab = ws + WS_ABUF + (size_t)n * DIN * DOUT;
    const float4 b4 = *(const float4*)(&bv[o0 + to * 4]);
    const float bs[4] = {b4.x, b4.y, b4.z, b4.w};
    #pragma unroll
    for (int r = 0; r < 4; ++r) {
        const int i = i0 + ti * 4 + r;
        const float ai = av[i];
        const float4 g4 = *(const float4*)(&Gb[(size_t)i * DOUT + o0 + to * 4]);
        const float4 m4 = *(const float4*)(&Mb[(size_t)i * DOUT + o0 + to * 4]);
        float4 res;
        res.x = m4.x + EPS * (acc[r][0] - ai * bs[0] * g4.x);
        res.y = m4.y + EPS * (acc[r][1] - ai * bs[1] * g4.y);
        res.z = m4.z + EPS * (acc[r][2] - ai * bs[2] * g4.z);
        res.w = m4.w + EPS * (acc[r][3] - ai * bs[3] * g4.w);
        *(float4*)(&Ab[(size_t)i * DOUT + o0 + to * 4]) = res;
    }
}

// ============================================================
// K5: Eh[n][p][o] = 0.5*( (A^T A)[p][o] - I ), overwrites T region.
// grid 1024, block 256.
// ============================================================
__global__ __launch_bounds__(256) void k_E(float* __restrict__ ws)
{
    __shared__ float sA[64][68];
    __shared__ float sB[64][68];
    const int n  = blockIdx.x >> 4;
    const int p0 = ((blockIdx.x >> 2) & 3) * 64;
    const int o0 = (blockIdx.x & 3) * 64;
    const int tid = threadIdx.x;
    const int to = tid & 15, tp = tid >> 4;
    const float* Ab = ws + WS_ABUF + (size_t)n * DIN * DOUT;

    float acc[4][4] = {};
    for (int kb = 0; kb < DIN; kb += 64) {
        #pragma unroll
        for (int t = 0; t < 16; ++t) {
            const int e = tid + t * 256;
            const int kk = e >> 6, cc = e & 63;
            sA[kk][cc] = Ab[(size_t)(kb + kk) * DOUT + p0 + cc];
            sB[kk][cc] = Ab[(size_t)(kb + kk) * DOUT + o0 + cc];
        }
        __syncthreads();
        #pragma unroll 8
        for (int kk = 0; kk < 64; ++kk) {
            const float4 a4 = *(const float4*)(&sA[kk][tp * 4]);
            const float4 b4 = *(const float4*)(&sB[kk][to * 4]);
            const float xs[4] = {a4.x, a4.y, a4.z, a4.w};
            const float ys[4] = {b4.x, b4.y, b4.z, b4.w};
            #pragma unroll
            for (int r = 0; r < 4; ++r)
                #pragma unroll
                for (int c = 0; c < 4; ++c)
                    acc[r][c] = fmaf(xs[r], ys[c], acc[r][c]);
        }
        __syncthreads();
    }
    float* Eh = ws + WS_T + (size_t)n * DOUT * DOUT;
    #pragma unroll
    for (int r = 0; r < 4; ++r) {
        const int p = p0 + tp * 4 + r;
        float4 res;
        res.x = 0.5f * acc[r][0]; res.y = 0.5f * acc[r][1];
        res.z = 0.5f * acc[r][2]; res.w = 0.5f * acc[r][3];
        const int ob = o0 + to * 4;
        if (p == ob + 0) res.x -= 0.5f;
        if (p == ob + 1) res.y -= 0.5f;
        if (p == ob + 2) res.z -= 0.5f;
        if (p == ob + 3) res.w -= 0.5f;
        *(float4*)(&Eh[(size_t)p * DOUT + ob]) = res;
    }
}

// ============================================================
// K6: Mnew[n][i][o] = A[i][o] - sum_p A[i][p]*Eh[p][o]   (one Newton step)
// grid 4096, block 256.
// ============================================================
__global__ __launch_bounds__(256) void k_Mnew(
    float* __restrict__ ws, float* __restrict__ out)
{
    __shared__ float sXt[64][68];
    __shared__ float sY[64][68];
    const int n  = blockIdx.x >> 6;
    const int i0 = ((blockIdx.x >> 2) & 15) * 64;
    const int o0 = (blockIdx.x & 3) * 64;
    const int tid = threadIdx.x;
    const int to = tid & 15, ti = tid >> 4;
    const float* Ab = ws + WS_ABUF + (size_t)n * DIN * DOUT;
    const float* Eh = ws + WS_T + (size_t)n * DOUT * DOUT;

    float acc[4][4] = {};
    for (int kb = 0; kb < DOUT; kb += 64) {
        #pragma unroll
        for (int t = 0; t < 16; ++t) {
            const int e = tid + t * 256;
            const int rr = e >> 6, cc = e & 63;
            sXt[cc][rr] = Ab[(size_t)(i0 + rr) * DOUT + kb + cc];
            sY[rr][cc]  = Eh[(size_t)(kb + rr) * DOUT + o0 + cc];
        }
        __syncthreads();
        #pragma unroll 8
        for (int kk = 0; kk < 64; ++kk) {
            const float4 x4 = *(const float4*)(&sXt[kk][ti * 4]);
            const float4 y4 = *(const float4*)(&sY[kk][to * 4]);
            const float xs[4] = {x4.x, x4.y, x4.z, x4.w};
            const float ys[4] = {y4.x, y4.y, y4.z, y4.w};
            #pragma unroll
            for (int r = 0; r < 4; ++r)
                #pragma unroll
                for (int c = 0; c < 4; ++c)
                    acc[r][c] = fmaf(xs[r], ys[c], acc[r][c]);
        }
        __syncthreads();
    }
    #pragma unroll
    for (int r = 0; r < 4; ++r) {
        const int i = i0 + ti * 4 + r;
        const float4 a4 = *(const float4*)(&Ab[(size_t)i * DOUT + o0 + to * 4]);
        float4 res;
        res.x = a4.x - acc[r][0]; res.y = a4.y - acc[r][1];
        res.z = a4.z - acc[r][2]; res.w = a4.w - acc[r][3];
        *(float4*)(&out[OUT_MNEW + (size_t)n * DIN * DOUT + (size_t)i * DOUT + o0 + to * 4]) = res;
    }
}

extern "C" void kernel_launch(void* const* d_in, const int* in_sizes, int n_in,
                              void* d_out, int out_size, void* d_ws, size_t ws_size,
                              hipStream_t stream) {
    const float* grad  = (const float*)d_in[0];
    const float* M     = (const float*)d_in[1];
    const float* state = (const float*)d_in[2];
    const float* L0    = (const float*)d_in[3];
    const float* R0    = (const float*)d_in[4];
    float* out = (float*)d_out;
    float* ws  = (float*)d_ws;

    k_moments<<<1024, 256, 0, stream>>>(grad, L0, out, ws);
    k_cols   <<<64,   256, 0, stream>>>(R0, state, out, ws);
    k_T      <<<1024, 256, 0, stream>>>(M, grad, ws);
    k_Abuild <<<4096, 256, 0, stream>>>(M, grad, ws);
    k_E      <<<1024, 256, 0, stream>>>(ws);
    k_Mnew   <<<4096, 256, 0, stream>>>(ws, out);
}

// Round 2
// 224.009 us; speedup vs baseline: 2.6687x; 2.6687x over previous
//
#include <hip/hip_runtime.h>

typedef unsigned short u16t;
typedef unsigned int   u32t;
typedef __bf16 bf16x8 __attribute__((ext_vector_type(8)));
typedef float  f32x4  __attribute__((ext_vector_type(4)));

#define NB   64
#define DIN  1024
#define DOUT 256
#define EPS  1e-4f   // LR*LR
#define KP   72      // LDS row stride in u16 (144B, 16B-aligned)

#define OUT_STATE (NB*DIN*DOUT)
#define OUT_LL    (OUT_STATE + 1)
#define OUT_RR    (OUT_LL + NB*DIN)

__device__ __forceinline__ u16t f2b(float x) {
    u32t u = __builtin_bit_cast(u32t, x);
    u += 0x7FFFu + ((u >> 16) & 1u);          // RTNE
    return (u16t)(u >> 16);
}
__device__ __forceinline__ float b2f(u16t h) {
    return __builtin_bit_cast(float, ((u32t)h) << 16);
}

// ============================================================
// K1: row moments -> ll (out), write GH = bf16(a_i * grad), col partials
// grid 1024 = 64n * 16 chunks, block 256
// ============================================================
__global__ __launch_bounds__(256) void k_moments(
    const float* __restrict__ grad, const float* __restrict__ L0,
    float* __restrict__ out, u16t* __restrict__ GH, float* __restrict__ CP)
{
    const int n = blockIdx.x >> 4, chunk = blockIdx.x & 15;
    const int wave = threadIdx.x >> 6, lane = threadIdx.x & 63;
    const float* gb = grad + ((size_t)n << 18);
    u16t* GHn = GH + ((size_t)n << 18);
    float4 cacc = {0.f, 0.f, 0.f, 0.f};
    const int i0 = chunk * 64 + wave * 16;
    for (int r = 0; r < 16; ++r) {
        const int i = i0 + r;
        const float4 v = *(const float4*)(gb + (size_t)i * 256 + lane * 4);
        float s = v.x*v.x + v.y*v.y + v.z*v.z + v.w*v.w;
        cacc.x += v.x*v.x; cacc.y += v.y*v.y; cacc.z += v.z*v.z; cacc.w += v.w*v.w;
        #pragma unroll
        for (int off = 32; off; off >>= 1) s += __shfl_xor(s, off);
        const float l0 = L0[n * DIN + i];
        const float ll = fmaxf(l0, 0.5f * l0 + s * (0.5f / DOUT));
        const float a  = rsqrtf(sqrtf(ll));
        ushort4 g4 = { f2b(v.x * a), f2b(v.y * a), f2b(v.z * a), f2b(v.w * a) };
        *(ushort4*)(GHn + (size_t)i * 256 + lane * 4) = g4;
        if (lane == 0) out[OUT_LL + n * DIN + i] = ll;
    }
    const int slot = chunk * 4 + wave;
    *(float4*)(CP + ((size_t)(n * 64 + slot)) * 256 + lane * 4) = cacc;
}

// ============================================================
// K2: reduce col partials -> rr (out), BS = rr^-1/4 ; copy state
// ============================================================
__global__ __launch_bounds__(256) void k_cols(
    const float* __restrict__ R0, const float* __restrict__ state,
    float* __restrict__ out, float* __restrict__ BS, const float* __restrict__ CP)
{
    const int n = blockIdx.x, o = threadIdx.x;
    const float* cp = CP + (size_t)n * 64 * 256 + o;
    float s = 0.f;
    #pragma unroll 8
    for (int k = 0; k < 64; ++k) s += cp[k * 256];
    const float r0 = R0[n * DOUT + o];
    const float rr = fmaxf(r0, 0.5f * r0 + s * (0.5f / DIN));
    out[OUT_RR + n * DOUT + o] = rr;
    BS[n * DOUT + o] = rsqrtf(sqrtf(rr));
    if (n == 0 && o == 0) out[OUT_STATE] = state[0];
}

// ============================================================
// K3: TT[o][p] = b[o] * sum_i GH[i][o] * M[i][p]   (T transposed), bf16 MFMA
// tile 128(o) x 64(p), K=1024. grid 512 = 64n * (2 o-tiles * 4 p-tiles)
// ============================================================
__global__ __launch_bounds__(256) void k_T(
    const float* __restrict__ M, const u16t* __restrict__ GH,
    const float* __restrict__ BS, u16t* __restrict__ TT)
{
    __shared__ u16t sA[128 * KP];   // [o][i]
    __shared__ u16t sB[64 * KP];    // [p][i]
    const int bx = blockIdx.x;
    const int n  = bx >> 3;
    const int o0 = ((bx >> 2) & 1) * 128;
    const int p0 = (bx & 3) * 64;
    const int tid = threadIdx.x;
    const int lane = tid & 63, w = tid >> 6, wr = w >> 1, wc = w & 1;
    const u16t* GHn = GH + ((size_t)n << 18);
    const float* Mn = M + ((size_t)n << 18);
    f32x4 acc[4][2] = {};
    for (int ic = 0; ic < 16; ++ic) {
        const int ib = ic * 64;
        __syncthreads();
        {   // stage A (transpose GH tile): sA[c][i]
            const int c4 = tid & 31, ipr = tid >> 5;
            #pragma unroll
            for (int it = 0; it < 4; ++it) {
                const int i = 2 * (ipr + 8 * it);
                const ushort4 r0 = *(const ushort4*)(GHn + (size_t)(ib+i  ) * 256 + o0 + c4*4);
                const ushort4 r1 = *(const ushort4*)(GHn + (size_t)(ib+i+1) * 256 + o0 + c4*4);
                *(u32t*)&sA[(c4*4+0)*KP + i] = (u32t)r0.x | ((u32t)r1.x << 16);
                *(u32t*)&sA[(c4*4+1)*KP + i] = (u32t)r0.y | ((u32t)r1.y << 16);
                *(u32t*)&sA[(c4*4+2)*KP + i] = (u32t)r0.z | ((u32t)r1.z << 16);
                *(u32t*)&sA[(c4*4+3)*KP + i] = (u32t)r0.w | ((u32t)r1.w << 16);
            }
        }
        {   // stage B (transpose + cvt M tile): sB[p][i]
            const int p4 = tid & 15, ipr = tid >> 4;
            #pragma unroll
            for (int it = 0; it < 2; ++it) {
                const int i = 2 * (ipr + 16 * it);
                const float4 f0 = *(const float4*)(Mn + (size_t)(ib+i  ) * 256 + p0 + p4*4);
                const float4 f1 = *(const float4*)(Mn + (size_t)(ib+i+1) * 256 + p0 + p4*4);
                *(u32t*)&sB[(p4*4+0)*KP + i] = (u32t)f2b(f0.x) | ((u32t)f2b(f1.x) << 16);
                *(u32t*)&sB[(p4*4+1)*KP + i] = (u32t)f2b(f0.y) | ((u32t)f2b(f1.y) << 16);
                *(u32t*)&sB[(p4*4+2)*KP + i] = (u32t)f2b(f0.z) | ((u32t)f2b(f1.z) << 16);
                *(u32t*)&sB[(p4*4+3)*KP + i] = (u32t)f2b(f0.w) | ((u32t)f2b(f1.w) << 16);
            }
        }
        __syncthreads();
        #pragma unroll
        for (int kb = 0; kb < 2; ++kb) {
            const int ko = kb * 32 + (lane >> 4) * 8;
            bf16x8 fa[4], fb[2];
            #pragma unroll
            for (int fm = 0; fm < 4; ++fm)
                fa[fm] = *(const bf16x8*)(sA + (wr*64 + fm*16 + (lane & 15)) * KP + ko);
            #pragma unroll
            for (int fn = 0; fn < 2; ++fn)
                fb[fn] = *(const bf16x8*)(sB + (wc*32 + fn*16 + (lane & 15)) * KP + ko);
            #pragma unroll
            for (int fm = 0; fm < 4; ++fm)
                #pragma unroll
                for (int fn = 0; fn < 2; ++fn)
                    acc[fm][fn] = __builtin_amdgcn_mfma_f32_16x16x32_bf16(fa[fm], fb[fn], acc[fm][fn], 0, 0, 0);
        }
    }
    const float* bs = BS + n * DOUT;
    u16t* TTn = TT + ((size_t)n << 16);
    #pragma unroll
    for (int fm = 0; fm < 4; ++fm)
        #pragma unroll
        for (int fn = 0; fn < 2; ++fn) {
            const int p = p0 + wc*32 + fn*16 + (lane & 15);
            #pragma unroll
            for (int r = 0; r < 4; ++r) {
                const int o = o0 + wr*64 + fm*16 + (lane >> 4)*4 + r;
                TTn[o * 256 + p] = f2b(acc[fm][fn][r] * bs[o]);
            }
        }
}

// ============================================================
// K4: A = M + EPS*( M*T - b_o*GH )  -> AH bf16. MT[i][o] = sum_p M[i][p]*TT[o][p]
// tile 128(i) x 64(o), K=256. grid 2048 = 64n * (8 i-tiles * 4 o-tiles)
// ============================================================
__global__ __launch_bounds__(256) void k_Abuild(
    const float* __restrict__ M, const u16t* __restrict__ GH,
    const float* __restrict__ BS, const u16t* __restrict__ TT,
    u16t* __restrict__ AH)
{
    __shared__ u16t sA[128 * KP];   // [i][p]
    __shared__ u16t sB[64 * KP];    // [o][p]
    const int bx = blockIdx.x;
    const int n  = bx >> 5;
    const int i0 = ((bx >> 2) & 7) * 128;
    const int o0 = (bx & 3) * 64;
    const int tid = threadIdx.x;
    const int lane = tid & 63, w = tid >> 6, wr = w >> 1, wc = w & 1;
    const float* Mn = M + ((size_t)n << 18);
    const u16t* GHn = GH + ((size_t)n << 18);
    const u16t* TTn = TT + ((size_t)n << 16);
    f32x4 acc[4][2] = {};
    for (int pc = 0; pc < 4; ++pc) {
        const int pb = pc * 64;
        __syncthreads();
        {   // stage A natural: sA[i][p] = bf16(M[i0+i][pb+p])
            const int p4 = tid & 15, rbase = tid >> 4;
            #pragma unroll
            for (int rt = 0; rt < 8; ++rt) {
                const int i = rbase + rt * 16;
                const float4 f = *(const float4*)(Mn + (size_t)(i0+i) * 256 + pb + p4*4);
                ushort4 h = { f2b(f.x), f2b(f.y), f2b(f.z), f2b(f.w) };
                *(ushort4*)&sA[i * KP + p4*4] = h;
            }
        }
        {   // stage B natural: sB[o][p] = TT[o0+o][pb+p]
            const int p4 = tid & 15, obase = tid >> 4;
            #pragma unroll
            for (int ot = 0; ot < 4; ++ot) {
                const int o = obase + ot * 16;
                *(ushort4*)&sB[o * KP + p4*4] =
                    *(const ushort4*)(TTn + (size_t)(o0+o) * 256 + pb + p4*4);
            }
        }
        __syncthreads();
        #pragma unroll
        for (int kb = 0; kb < 2; ++kb) {
            const int ko = kb * 32 + (lane >> 4) * 8;
            bf16x8 fa[4], fb[2];
            #pragma unroll
            for (int fm = 0; fm < 4; ++fm)
                fa[fm] = *(const bf16x8*)(sA + (wr*64 + fm*16 + (lane & 15)) * KP + ko);
            #pragma unroll
            for (int fn = 0; fn < 2; ++fn)
                fb[fn] = *(const bf16x8*)(sB + (wc*32 + fn*16 + (lane & 15)) * KP + ko);
            #pragma unroll
            for (int fm = 0; fm < 4; ++fm)
                #pragma unroll
                for (int fn = 0; fn < 2; ++fn)
                    acc[fm][fn] = __builtin_amdgcn_mfma_f32_16x16x32_bf16(fa[fm], fb[fn], acc[fm][fn], 0, 0, 0);
        }
    }
    const float* bs = BS + n * DOUT;
    u16t* AHn = AH + ((size_t)n << 18);
    #pragma unroll
    for (int fm = 0; fm < 4; ++fm)
        #pragma unroll
        for (int fn = 0; fn < 2; ++fn) {
            const int o = o0 + wc*32 + fn*16 + (lane & 15);
            const float bo = bs[o];
            #pragma unroll
            for (int r = 0; r < 4; ++r) {
                const int i = i0 + wr*64 + fm*16 + (lane >> 4)*4 + r;
                const size_t idx = (size_t)i * 256 + o;
                const float Aval = Mn[idx] + EPS * (acc[fm][fn][r] - bo * b2f(GHn[idx]));
                AHn[idx] = f2b(Aval);
            }
        }
}

// ============================================================
// K5: EH[p][o] = bf16( 0.5*(A^T A - I) ).  tile 128(p) x 64(o), K=1024.
// grid 512 = 64n * (2 p-tiles * 4 o-tiles)
// ============================================================
__global__ __launch_bounds__(256) void k_E(
    const u16t* __restrict__ AH, u16t* __restrict__ EH)
{
    __shared__ u16t sA[128 * KP];   // [p][i]
    __shared__ u16t sB[64 * KP];    // [o][i]
    const int bx = blockIdx.x;
    const int n  = bx >> 3;
    const int p0 = ((bx >> 2) & 1) * 128;
    const int o0 = (bx & 3) * 64;
    const int tid = threadIdx.x;
    const int lane = tid & 63, w = tid >> 6, wr = w >> 1, wc = w & 1;
    const u16t* AHn = AH + ((size_t)n << 18);
    f32x4 acc[4][2] = {};
    for (int ic = 0; ic < 16; ++ic) {
        const int ib = ic * 64;
        __syncthreads();
        {   // stage A (transpose): sA[c][i] = AH[ib+i][p0+c], c<128
            const int c4 = tid & 31, ipr = tid >> 5;
            #pragma unroll
            for (int it = 0; it < 4; ++it) {
                const int i = 2 * (ipr + 8 * it);
                const ushort4 r0 = *(const ushort4*)(AHn + (size_t)(ib+i  ) * 256 + p0 + c4*4);
                const ushort4 r1 = *(const ushort4*)(AHn + (size_t)(ib+i+1) * 256 + p0 + c4*4);
                *(u32t*)&sA[(c4*4+0)*KP + i] = (u32t)r0.x | ((u32t)r1.x << 16);
                *(u32t*)&sA[(c4*4+1)*KP + i] = (u32t)r0.y | ((u32t)r1.y << 16);
                *(u32t*)&sA[(c4*4+2)*KP + i] = (u32t)r0.z | ((u32t)r1.z << 16);
                *(u32t*)&sA[(c4*4+3)*KP + i] = (u32t)r0.w | ((u32t)r1.w << 16);
            }
        }
        {   // stage B (transpose): sB[c][i] = AH[ib+i][o0+c], c<64
            const int c4 = tid & 15, ipr = tid >> 4;
            #pragma unroll
            for (int it = 0; it < 2; ++it) {
                const int i = 2 * (ipr + 16 * it);
                const ushort4 r0 = *(const ushort4*)(AHn + (size_t)(ib+i  ) * 256 + o0 + c4*4);
                const ushort4 r1 = *(const ushort4*)(AHn + (size_t)(ib+i+1) * 256 + o0 + c4*4);
                *(u32t*)&sB[(c4*4+0)*KP + i] = (u32t)r0.x | ((u32t)r1.x << 16);
                *(u32t*)&sB[(c4*4+1)*KP + i] = (u32t)r0.y | ((u32t)r1.y << 16);
                *(u32t*)&sB[(c4*4+2)*KP + i] = (u32t)r0.z | ((u32t)r1.z << 16);
                *(u32t*)&sB[(c4*4+3)*KP + i] = (u32t)r0.w | ((u32t)r1.w << 16);
            }
        }
        __syncthreads();
        #pragma unroll
        for (int kb = 0; kb < 2; ++kb) {
            const int ko = kb * 32 + (lane >> 4) * 8;
            bf16x8 fa[4], fb[2];
            #pragma unroll
            for (int fm = 0; fm < 4; ++fm)
                fa[fm] = *(const bf16x8*)(sA + (wr*64 + fm*16 + (lane & 15)) * KP + ko);
            #pragma unroll
            for (int fn = 0; fn < 2; ++fn)
                fb[fn] = *(const bf16x8*)(sB + (wc*32 + fn*16 + (lane & 15)) * KP + ko);
            #pragma unroll
            for (int fm = 0; fm < 4; ++fm)
                #pragma unroll
                for (int fn = 0; fn < 2; ++fn)
                    acc[fm][fn] = __builtin_amdgcn_mfma_f32_16x16x32_bf16(fa[fm], fb[fn], acc[fm][fn], 0, 0, 0);
        }
    }
    u16t* EHn = EH + ((size_t)n << 16);
    #pragma unroll
    for (int fm = 0; fm < 4; ++fm)
        #pragma unroll
        for (int fn = 0; fn < 2; ++fn) {
            const int o = o0 + wc*32 + fn*16 + (lane & 15);
            #pragma unroll
            for (int r = 0; r < 4; ++r) {
                const int p = p0 + wr*64 + fm*16 + (lane >> 4)*4 + r;
                const float v = 0.5f * acc[fm][fn][r] - (p == o ? 0.5f : 0.f);
                EHn[p * 256 + o] = f2b(v);
            }
        }
}

// ============================================================
// K6: Mnew[i][o] = A[i][o] - sum_p AH[i][p] * EH[p][o]   (Eh symmetric)
// tile 128(i) x 64(o), K=256. grid 2048
// ============================================================
__global__ __launch_bounds__(256) void k_Mnew(
    const u16t* __restrict__ AH, const u16t* __restrict__ EH,
    float* __restrict__ out)
{
    __shared__ u16t sA[128 * KP];   // [i][p]
    __shared__ u16t sB[64 * KP];    // [o][p]  ( = Eh[p][o] by symmetry)
    const int bx = blockIdx.x;
    const int n  = bx >> 5;
    const int i0 = ((bx >> 2) & 7) * 128;
    const int o0 = (bx & 3) * 64;
    const int tid = threadIdx.x;
    const int lane = tid & 63, w = tid >> 6, wr = w >> 1, wc = w & 1;
    const u16t* AHn = AH + ((size_t)n << 18);
    const u16t* EHn = EH + ((size_t)n << 16);
    f32x4 acc[4][2] = {};
    for (int pc = 0; pc < 4; ++pc) {
        const int pb = pc * 64;
        __syncthreads();
        {   // stage A natural copy: sA[i][p] = AH[i0+i][pb+p]
            const int p4 = tid & 15, rbase = tid >> 4;
            #pragma unroll
            for (int rt = 0; rt < 8; ++rt) {
                const int i = rbase + rt * 16;
                *(ushort4*)&sA[i * KP + p4*4] =
                    *(const ushort4*)(AHn + (size_t)(i0+i) * 256 + pb + p4*4);
            }
        }
        {   // stage B: sB[o][p] = EH[o0+o][pb+p]  (row o of symmetric Eh)
            const int p4 = tid & 15, obase = tid >> 4;
            #pragma unroll
            for (int ot = 0; ot < 4; ++ot) {
                const int o = obase + ot * 16;
                *(ushort4*)&sB[o * KP + p4*4] =
                    *(const ushort4*)(EHn + (size_t)(o0+o) * 256 + pb + p4*4);
            }
        }
        __syncthreads();
        #pragma unroll
        for (int kb = 0; kb < 2; ++kb) {
            const int ko = kb * 32 + (lane >> 4) * 8;
            bf16x8 fa[4], fb[2];
            #pragma unroll
            for (int fm = 0; fm < 4; ++fm)
                fa[fm] = *(const bf16x8*)(sA + (wr*64 + fm*16 + (lane & 15)) * KP + ko);
            #pragma unroll
            for (int fn = 0; fn < 2; ++fn)
                fb[fn] = *(const bf16x8*)(sB + (wc*32 + fn*16 + (lane & 15)) * KP + ko);
            #pragma unroll
            for (int fm = 0; fm < 4; ++fm)
                #pragma unroll
                for (int fn = 0; fn < 2; ++fn)
                    acc[fm][fn] = __builtin_amdgcn_mfma_f32_16x16x32_bf16(fa[fm], fb[fn], acc[fm][fn], 0, 0, 0);
        }
    }
    #pragma unroll
    for (int fm = 0; fm < 4; ++fm)
        #pragma unroll
        for (int fn = 0; fn < 2; ++fn) {
            const int o = o0 + wc*32 + fn*16 + (lane & 15);
            #pragma unroll
            for (int r = 0; r < 4; ++r) {
                const int i = i0 + wr*64 + fm*16 + (lane >> 4)*4 + r;
                const size_t idx = (size_t)i * 256 + o;
                out[((size_t)n << 18) + idx] = b2f(AHn[idx]) - acc[fm][fn][r];
            }
        }
}

extern "C" void kernel_launch(void* const* d_in, const int* in_sizes, int n_in,
                              void* d_out, int out_size, void* d_ws, size_t ws_size,
                              hipStream_t stream) {
    const float* grad  = (const float*)d_in[0];
    const float* M     = (const float*)d_in[1];
    const float* state = (const float*)d_in[2];
    const float* L0    = (const float*)d_in[3];
    const float* R0    = (const float*)d_in[4];
    float* out = (float*)d_out;
    char* wsb = (char*)d_ws;

    u16t* GH = (u16t*)(wsb);                                 // 32 MB  bf16 a*grad
    u16t* AH = (u16t*)(wsb + (size_t)32 * 1024 * 1024);      // 32 MB  bf16 A
    u16t* TT = (u16t*)(wsb + (size_t)64 * 1024 * 1024);      //  8 MB  bf16 T^T
    u16t* EH = (u16t*)(wsb + (size_t)72 * 1024 * 1024);      //  8 MB  bf16 Eh
    float* BS = (float*)(wsb + (size_t)80 * 1024 * 1024);    // 64 KB  rr^-1/4
    float* CP = (float*)(wsb + (size_t)81 * 1024 * 1024);    //  4 MB  col partials

    k_moments<<<1024, 256, 0, stream>>>(grad, L0, out, GH, CP);
    k_cols   <<<64,   256, 0, stream>>>(R0, state, out, BS, CP);
    k_T      <<<512,  256, 0, stream>>>(M, GH, BS, TT);
    k_Abuild <<<2048, 256, 0, stream>>>(M, GH, BS, TT, AH);
    k_E      <<<512,  256, 0, stream>>>(AH, EH);
    k_Mnew   <<<2048, 256, 0, stream>>>(AH, EH, out);
}

// Round 3
// 180.539 us; speedup vs baseline: 3.3113x; 1.2408x over previous
//
#include <hip/hip_runtime.h>

typedef unsigned short u16t;
typedef unsigned int   u32t;
typedef __bf16 bf16x8 __attribute__((ext_vector_type(8)));
typedef float  f32x4  __attribute__((ext_vector_type(4)));

#define NB   64
#define DIN  1024
#define DOUT 256
#define EPS  1e-4f   // LR*LR
#define KP   68      // LDS row stride in u16: 34 dwords == 2 mod 32 -> conflict-free patterns

#define OUT_STATE (NB*DIN*DOUT)
#define OUT_LL    (OUT_STATE + 1)
#define OUT_RR    (OUT_LL + NB*DIN)

__device__ __forceinline__ u16t f2b(float x) {
    u32t u = __builtin_bit_cast(u32t, x);
    u += 0x7FFFu + ((u >> 16) & 1u);          // RTNE
    return (u16t)(u >> 16);
}
__device__ __forceinline__ float b2f(u16t h) {
    return __builtin_bit_cast(float, ((u32t)h) << 16);
}
// 16B fragment from 8B-aligned LDS (two ds_read_b64)
__device__ __forceinline__ bf16x8 ld_frag(const u16t* p) {
    uint2 lo = *(const uint2*)(p);
    uint2 hi = *(const uint2*)(p + 4);
    union { uint4 u; bf16x8 v; } x;
    x.u = make_uint4(lo.x, lo.y, hi.x, hi.y);
    return x.v;
}
__device__ __forceinline__ void st8(u16t* p, u32t a, u32t b) {
    *(uint2*)(p) = make_uint2(a, b);
}

// ============================================================
// K1: grad row moments -> ll, GH = bf16(a*grad); col partials CP;
//     M chunk -> LDS transpose -> MHT bf16.
// grid 1024 = (n, 16 i-chunks), block 256. XCD: bid&7 = n&7.
// ============================================================
__global__ __launch_bounds__(256) void k_prep(
    const float* __restrict__ grad, const float* __restrict__ M,
    const float* __restrict__ L0, float* __restrict__ out,
    u16t* __restrict__ GH, u16t* __restrict__ MHT, float* __restrict__ CP)
{
    __shared__ u16t sT[256 * KP];
    const int bid = blockIdx.x;
    const int n = (bid & 7) | ((bid >> 7) << 3);
    const int chunk = (bid >> 3) & 15;
    const int tid = threadIdx.x, wave = tid >> 6, lane = tid & 63;
    const int ib = chunk * 64;
    const float* gb = grad + ((size_t)n << 18);
    const float* Mb = M + ((size_t)n << 18);
    u16t* GHn = GH + ((size_t)n << 18);

    float4 cacc = {0.f, 0.f, 0.f, 0.f};
    #pragma unroll 4
    for (int r = 0; r < 16; ++r) {
        const int i = ib + wave * 16 + r;
        const float4 v = *(const float4*)(gb + (size_t)i * 256 + lane * 4);
        float s = v.x*v.x + v.y*v.y + v.z*v.z + v.w*v.w;
        cacc.x += v.x*v.x; cacc.y += v.y*v.y; cacc.z += v.z*v.z; cacc.w += v.w*v.w;
        #pragma unroll
        for (int off = 32; off; off >>= 1) s += __shfl_xor(s, off);
        const float l0 = L0[n * DIN + i];
        const float ll = fmaxf(l0, 0.5f * l0 + s * (0.5f / DOUT));
        const float a  = rsqrtf(sqrtf(ll));
        ushort4 g4 = { f2b(v.x*a), f2b(v.y*a), f2b(v.z*a), f2b(v.w*a) };
        *(ushort4*)(GHn + (size_t)i * 256 + lane * 4) = g4;
        if (lane == 0) out[OUT_LL + n * DIN + i] = ll;
    }
    const int slot = chunk * 4 + wave;
    *(float4*)(CP + ((size_t)(n * 64 + slot)) * 256 + lane * 4) = cacc;

    // M transpose: sT[p][i_local]
    #pragma unroll 4
    for (int r = 0; r < 16; ++r) {
        const int il = wave * 16 + r;
        const float4 v = *(const float4*)(Mb + (size_t)(ib + il) * 256 + lane * 4);
        sT[(lane*4 + 0) * KP + il] = f2b(v.x);
        sT[(lane*4 + 1) * KP + il] = f2b(v.y);
        sT[(lane*4 + 2) * KP + il] = f2b(v.z);
        sT[(lane*4 + 3) * KP + il] = f2b(v.w);
    }
    __syncthreads();
    u16t* MT = MHT + ((size_t)n << 18);
    #pragma unroll
    for (int q = 0; q < 8; ++q) {
        const int row = (tid >> 3) + 32 * q;
        const int c8  = (tid & 7) * 8;
        uint2 lo = *(const uint2*)(sT + row * KP + c8);
        uint2 hi = *(const uint2*)(sT + row * KP + c8 + 4);
        uint4 v4 = make_uint4(lo.x, lo.y, hi.x, hi.y);
        *(uint4*)(MT + (size_t)row * 1024 + ib + c8) = v4;
    }
}

// ============================================================
// K2: reduce col partials -> rr (out), BS = rr^-1/4 ; copy state
// ============================================================
__global__ __launch_bounds__(256) void k_cols(
    const float* __restrict__ R0, const float* __restrict__ state,
    float* __restrict__ out, float* __restrict__ BS, const float* __restrict__ CP)
{
    const int n = blockIdx.x, o = threadIdx.x;
    const float* cp = CP + (size_t)n * 64 * 256 + o;
    float s = 0.f;
    #pragma unroll 8
    for (int k = 0; k < 64; ++k) s += cp[k * 256];
    const float r0 = R0[n * DOUT + o];
    const float rr = fmaxf(r0, 0.5f * r0 + s * (0.5f / DIN));
    out[OUT_RR + n * DOUT + o] = rr;
    BS[n * DOUT + o] = rsqrtf(sqrtf(rr));
    if (n == 0 && o == 0) out[OUT_STATE] = state[0];
}

// ============================================================
// G1 (k_T): TT[o][p] = b[o] * sum_i GH[i][o] * MHT[p][i]
// tile 128o x 128p, K=1024. grid 256 = (n, 4 tiles). XCD swizzle.
// ============================================================
__global__ __launch_bounds__(256, 3) void k_T(
    const u16t* __restrict__ GH, const u16t* __restrict__ MHT,
    const float* __restrict__ BS, u16t* __restrict__ TT)
{
    __shared__ u16t sA[128 * KP];   // [o][i]
    __shared__ u16t sB[128 * KP];   // [p][i]
    const int bid = blockIdx.x;
    const int n = (bid & 7) | ((bid >> 5) << 3);
    const int tile = (bid >> 3) & 3;
    const int o0 = (tile & 1) * 128, p0 = (tile >> 1) * 128;
    const int tid = threadIdx.x, lane = tid & 63, w = tid >> 6;
    const int wr = w >> 1, wc = w & 1, t16 = lane & 15, g4 = lane >> 4;
    const u16t* GHn = GH + ((size_t)n << 18);
    const u16t* MTn = MHT + ((size_t)n << 18);
    f32x4 acc[4][4] = {};
    for (int ch = 0; ch < 16; ++ch) {
        const int ib = ch * 64;
        __syncthreads();
        // sA: transpose-stage GH rows (o-major). 2-way free (bank = 2*lane + c)
        #pragma unroll
        for (int r = 0; r < 16; ++r) {
            const int il = w * 16 + r;
            const u16t* src = GHn + (size_t)(ib + il) * 256 + o0;
            sA[(size_t)lane * KP + il]        = src[lane];
            sA[(size_t)(lane + 64) * KP + il] = src[lane + 64];
        }
        // sB: natural rows from MHT
        #pragma unroll
        for (int q = 0; q < 4; ++q) {
            const int row = (tid >> 3) + 32 * q;
            const int c8  = (tid & 7) * 8;
            uint4 v = *(const uint4*)(MTn + (size_t)(p0 + row) * 1024 + ib + c8);
            st8(sB + row * KP + c8, v.x, v.y);
            st8(sB + row * KP + c8 + 4, v.z, v.w);
        }
        __syncthreads();
        #pragma unroll
        for (int kb = 0; kb < 2; ++kb) {
            const int ko = kb * 32 + g4 * 8;
            bf16x8 fa[4], fb[4];
            #pragma unroll
            for (int fm = 0; fm < 4; ++fm)
                fa[fm] = ld_frag(sA + (wr*64 + fm*16 + t16) * KP + ko);
            #pragma unroll
            for (int fn = 0; fn < 4; ++fn)
                fb[fn] = ld_frag(sB + (wc*64 + fn*16 + t16) * KP + ko);
            #pragma unroll
            for (int fm = 0; fm < 4; ++fm)
                #pragma unroll
                for (int fn = 0; fn < 4; ++fn)
                    acc[fm][fn] = __builtin_amdgcn_mfma_f32_16x16x32_bf16(fa[fm], fb[fn], acc[fm][fn], 0, 0, 0);
        }
    }
    const float* bs = BS + n * DOUT;
    u16t* TTn = TT + ((size_t)n << 16);
    #pragma unroll
    for (int fm = 0; fm < 4; ++fm)
        #pragma unroll
        for (int fn = 0; fn < 4; ++fn) {
            const int p = p0 + wc*64 + fn*16 + t16;
            #pragma unroll
            for (int r = 0; r < 4; ++r) {
                const int o = o0 + wr*64 + fm*16 + g4*4 + r;
                TTn[o * 256 + p] = f2b(acc[fm][fn][r] * bs[o]);
            }
        }
}

// ============================================================
// G2 (k_Abuild): A[i][o] = M + EPS*( sum_p M[i][p]*TT[o][p] - b_o*GH[i][o] )
// tile 128i x 256o (full), K=256. grid 512 = (n, 8 i-tiles). -> AH bf16
// ============================================================
__global__ __launch_bounds__(256, 2) void k_Abuild(
    const float* __restrict__ M, const u16t* __restrict__ GH,
    const float* __restrict__ BS, const u16t* __restrict__ TT,
    u16t* __restrict__ AH)
{
    __shared__ u16t sA[128 * KP];   // [i][p]
    __shared__ u16t sB[256 * KP];   // [o][p]
    const int bid = blockIdx.x;
    const int n = (bid & 7) | ((bid >> 6) << 3);
    const int i0 = ((bid >> 3) & 7) * 128;
    const int tid = threadIdx.x, lane = tid & 63, w = tid >> 6;
    const int wr = w >> 1, wc = w & 1, t16 = lane & 15, g4 = lane >> 4;
    const float* Mn = M + ((size_t)n << 18);
    const u16t* GHn = GH + ((size_t)n << 18);
    const u16t* TTn = TT + ((size_t)n << 16);
    f32x4 acc[4][8] = {};
    for (int ch = 0; ch < 4; ++ch) {
        const int pb = ch * 64;
        __syncthreads();
        // sA: convert fp32 M rows
        #pragma unroll
        for (int q = 0; q < 8; ++q) {
            const int row = (tid >> 4) + 16 * q;
            const int c4  = tid & 15;
            const float4 v = *(const float4*)(Mn + (size_t)(i0 + row) * 256 + pb + c4 * 4);
            ushort4 h = { f2b(v.x), f2b(v.y), f2b(v.z), f2b(v.w) };
            *(ushort4*)(sA + row * KP + c4 * 4) = h;
        }
        // sB: TT rows
        #pragma unroll
        for (int q = 0; q < 8; ++q) {
            const int row = (tid >> 3) + 32 * q;
            const int c8  = (tid & 7) * 8;
            uint4 v = *(const uint4*)(TTn + (size_t)row * 256 + pb + c8);
            st8(sB + row * KP + c8, v.x, v.y);
            st8(sB + row * KP + c8 + 4, v.z, v.w);
        }
        __syncthreads();
        #pragma unroll
        for (int kb = 0; kb < 2; ++kb) {
            const int ko = kb * 32 + g4 * 8;
            bf16x8 fa[4], fb[8];
            #pragma unroll
            for (int fm = 0; fm < 4; ++fm)
                fa[fm] = ld_frag(sA + (wr*64 + fm*16 + t16) * KP + ko);
            #pragma unroll
            for (int fn = 0; fn < 8; ++fn)
                fb[fn] = ld_frag(sB + (wc*128 + fn*16 + t16) * KP + ko);
            #pragma unroll
            for (int fm = 0; fm < 4; ++fm)
                #pragma unroll
                for (int fn = 0; fn < 8; ++fn)
                    acc[fm][fn] = __builtin_amdgcn_mfma_f32_16x16x32_bf16(fa[fm], fb[fn], acc[fm][fn], 0, 0, 0);
        }
    }
    const float* bs = BS + n * DOUT;
    u16t* AHn = AH + ((size_t)n << 18);
    #pragma unroll
    for (int fm = 0; fm < 4; ++fm)
        #pragma unroll
        for (int fn = 0; fn < 8; ++fn) {
            const int o = wc*128 + fn*16 + t16;
            const float bo = bs[o];
            #pragma unroll
            for (int r = 0; r < 4; ++r) {
                const int i = i0 + wr*64 + fm*16 + g4*4 + r;
                const size_t idx = (size_t)i * 256 + o;
                const float Aval = Mn[idx] + EPS * (acc[fm][fn][r] - bo * b2f(GHn[idx]));
                AHn[idx] = f2b(Aval);
            }
        }
}

// ============================================================
// G3 (k_E): EH[p][o] = bf16( 0.5*(A^T A - I) ). tile 128p x 128o, K=1024.
// grid 256 = (n, 4 tiles). Both operands transpose-staged from AH.
// ============================================================
__global__ __launch_bounds__(256, 3) void k_E(
    const u16t* __restrict__ AH, u16t* __restrict__ EH)
{
    __shared__ u16t sA[128 * KP];   // [p][i]
    __shared__ u16t sB[128 * KP];   // [o][i]
    const int bid = blockIdx.x;
    const int n = (bid & 7) | ((bid >> 5) << 3);
    const int tile = (bid >> 3) & 3;
    const int p0 = (tile >> 1) * 128, o0 = (tile & 1) * 128;
    const bool diag = (p0 == o0);
    const int tid = threadIdx.x, lane = tid & 63, w = tid >> 6;
    const int wr = w >> 1, wc = w & 1, t16 = lane & 15, g4 = lane >> 4;
    const u16t* AHn = AH + ((size_t)n << 18);
    f32x4 acc[4][4] = {};
    for (int ch = 0; ch < 16; ++ch) {
        const int ib = ch * 64;
        __syncthreads();
        #pragma unroll
        for (int r = 0; r < 16; ++r) {
            const int il = w * 16 + r;
            const u16t* src = AHn + (size_t)(ib + il) * 256;
            sA[(size_t)lane * KP + il]        = src[p0 + lane];
            sA[(size_t)(lane + 64) * KP + il] = src[p0 + lane + 64];
        }
        if (!diag) {
            #pragma unroll
            for (int r = 0; r < 16; ++r) {
                const int il = w * 16 + r;
                const u16t* src = AHn + (size_t)(ib + il) * 256;
                sB[(size_t)lane * KP + il]        = src[o0 + lane];
                sB[(size_t)(lane + 64) * KP + il] = src[o0 + lane + 64];
            }
        }
        __syncthreads();
        const u16t* sBr = diag ? sA : sB;
        #pragma unroll
        for (int kb = 0; kb < 2; ++kb) {
            const int ko = kb * 32 + g4 * 8;
            bf16x8 fa[4], fb[4];
            #pragma unroll
            for (int fm = 0; fm < 4; ++fm)
                fa[fm] = ld_frag(sA + (wr*64 + fm*16 + t16) * KP + ko);
            #pragma unroll
            for (int fn = 0; fn < 4; ++fn)
                fb[fn] = ld_frag(sBr + (wc*64 + fn*16 + t16) * KP + ko);
            #pragma unroll
            for (int fm = 0; fm < 4; ++fm)
                #pragma unroll
                for (int fn = 0; fn < 4; ++fn)
                    acc[fm][fn] = __builtin_amdgcn_mfma_f32_16x16x32_bf16(fa[fm], fb[fn], acc[fm][fn], 0, 0, 0);
        }
    }
    u16t* EHn = EH + ((size_t)n << 16);
    #pragma unroll
    for (int fm = 0; fm < 4; ++fm)
        #pragma unroll
        for (int fn = 0; fn < 4; ++fn) {
            const int o = o0 + wc*64 + fn*16 + t16;
            #pragma unroll
            for (int r = 0; r < 4; ++r) {
                const int p = p0 + wr*64 + fm*16 + g4*4 + r;
                const float v = 0.5f * acc[fm][fn][r] - (p == o ? 0.5f : 0.f);
                EHn[p * 256 + o] = f2b(v);
            }
        }
}

// ============================================================
// G4 (k_Mnew): Mnew[i][o] = b2f(AH[i][o]) - sum_p AH[i][p]*EH[o][p] (EH sym)
// tile 128i x 256o, K=256. grid 512 = (n, 8 i-tiles).
// ============================================================
__global__ __launch_bounds__(256, 2) void k_Mnew(
    const u16t* __restrict__ AH, const u16t* __restrict__ EH,
    float* __restrict__ out)
{
    __shared__ u16t sA[128 * KP];   // [i][p]
    __shared__ u16t sB[256 * KP];   // [o][p]
    const int bid = blockIdx.x;
    const int n = (bid & 7) | ((bid >> 6) << 3);
    const int i0 = ((bid >> 3) & 7) * 128;
    const int tid = threadIdx.x, lane = tid & 63, w = tid >> 6;
    const int wr = w >> 1, wc = w & 1, t16 = lane & 15, g4 = lane >> 4;
    const u16t* AHn = AH + ((size_t)n << 18);
    const u16t* EHn = EH + ((size_t)n << 16);
    f32x4 acc[4][8] = {};
    for (int ch = 0; ch < 4; ++ch) {
        const int pb = ch * 64;
        __syncthreads();
        #pragma unroll
        for (int q = 0; q < 4; ++q) {
            const int row = (tid >> 3) + 32 * q;
            const int c8  = (tid & 7) * 8;
            uint4 v = *(const uint4*)(AHn + (size_t)(i0 + row) * 256 + pb + c8);
            st8(sA + row * KP + c8, v.x, v.y);
            st8(sA + row * KP + c8 + 4, v.z, v.w);
        }
        #pragma unroll
        for (int q = 0; q < 8; ++q) {
            const int row = (tid >> 3) + 32 * q;
            const int c8  = (tid & 7) * 8;
            uint4 v = *(const uint4*)(EHn + (size_t)row * 256 + pb + c8);
            st8(sB + row * KP + c8, v.x, v.y);
            st8(sB + row * KP + c8 + 4, v.z, v.w);
        }
        __syncthreads();
        #pragma unroll
        for (int kb = 0; kb < 2; ++kb) {
            const int ko = kb * 32 + g4 * 8;
            bf16x8 fa[4], fb[8];
            #pragma unroll
            for (int fm = 0; fm < 4; ++fm)
                fa[fm] = ld_frag(sA + (wr*64 + fm*16 + t16) * KP + ko);
            #pragma unroll
            for (int fn = 0; fn < 8; ++fn)
                fb[fn] = ld_frag(sB + (wc*128 + fn*16 + t16) * KP + ko);
            #pragma unroll
            for (int fm = 0; fm < 4; ++fm)
                #pragma unroll
                for (int fn = 0; fn < 8; ++fn)
                    acc[fm][fn] = __builtin_amdgcn_mfma_f32_16x16x32_bf16(fa[fm], fb[fn], acc[fm][fn], 0, 0, 0);
        }
    }
    float* outn = out + ((size_t)n << 18);
    #pragma unroll
    for (int fm = 0; fm < 4; ++fm)
        #pragma unroll
        for (int fn = 0; fn < 8; ++fn) {
            const int o = wc*128 + fn*16 + t16;
            #pragma unroll
            for (int r = 0; r < 4; ++r) {
                const int i = i0 + wr*64 + fm*16 + g4*4 + r;
                const size_t idx = (size_t)i * 256 + o;
                outn[idx] = b2f(AHn[idx]) - acc[fm][fn][r];
            }
        }
}

extern "C" void kernel_launch(void* const* d_in, const int* in_sizes, int n_in,
                              void* d_out, int out_size, void* d_ws, size_t ws_size,
                              hipStream_t stream) {
    const float* grad  = (const float*)d_in[0];
    const float* M     = (const float*)d_in[1];
    const float* state = (const float*)d_in[2];
    const float* L0    = (const float*)d_in[3];
    const float* R0    = (const float*)d_in[4];
    float* out = (float*)d_out;
    char* wsb = (char*)d_ws;

    // region map (73 MB total):
    u16t* GH  = (u16t*)(wsb);                          // [0,32MB)   GH[n][i][o]
    u16t* MHT = (u16t*)(wsb + ((size_t)32 << 20));     // [32,64MB)  MHT[n][p][i]
    u16t* AH  = MHT;                                   // AH aliases MHT (dead after k_T)
    u16t* TT  = (u16t*)(wsb + ((size_t)64 << 20));     // [64,72MB)  TT[n][o][p]
    float* CP = (float*)TT;                            // CP aliases TT (dead after k_cols)
    u16t* EH  = TT;                                    // EH aliases TT (dead after k_Abuild)
    float* BS = (float*)(wsb + ((size_t)72 << 20));    // 64KB

    k_prep  <<<1024, 256, 0, stream>>>(grad, M, L0, out, GH, MHT, CP);
    k_cols  <<<64,   256, 0, stream>>>(R0, state, out, BS, CP);
    k_T     <<<256,  256, 0, stream>>>(GH, MHT, BS, TT);
    k_Abuild<<<512,  256, 0, stream>>>(M, GH, BS, TT, AH);
    k_E     <<<256,  256, 0, stream>>>(AH, EH);
    k_Mnew  <<<512,  256, 0, stream>>>(AH, EH, out);
}